// Round 4
// baseline (187.170 us; speedup 1.0000x reference)
//
#include <hip/hip_runtime.h>

#define DIMN 64
#define NNB 16
#define NREL 33
#define MH 8           // hop-1 neighbors handled per wave (16 / 2 waves)
#define XSTR 68        // LDS tile row stride in floats (pad: 2-way banks = free)

typedef float  floatx4 __attribute__((ext_vector_type(4)));
typedef short  shortx8 __attribute__((ext_vector_type(8)));

__device__ __forceinline__ float bcastf(float x, int lane) {
    return __int_as_float(__builtin_amdgcn_readlane(__float_as_int(x), lane));
}

// ---- prep: split W0 (fp32 64x64) into bf16 hi/lo MFMA B-fragments in d_ws ----
// frag f = kstep*4 + t  (kstep: K 0..31 / 32..63, t: N-tile of 16 cols)
// B-frag lane l holds B[k = kstep*32 + (l>>4)*8 + j][n = t*16 + (l&15)], j=0..7
// ws layout (ushort): hi[f][lane][8] at (f*64+l)*8 ; lo at 4096 + same
__global__ void prep_w0_frags(const float* __restrict__ W0, unsigned short* __restrict__ wsp) {
    const int tid = blockIdx.x * blockDim.x + threadIdx.x;   // 0..511
    if (tid >= 512) return;
    const int l = tid & 63;
    const int t = (tid >> 6) & 3;
    const int ks = tid >> 8;
    const int k0 = ks * 32 + (l >> 4) * 8;
    const int n  = t * 16 + (l & 15);
    const unsigned base = ((unsigned)(ks * 4 + t) * 64 + l) * 8;
    #pragma unroll
    for (int j = 0; j < 8; ++j) {
        const float x = W0[(k0 + j) * DIMN + n];
        const unsigned u  = __float_as_uint(x);
        const unsigned uh = u & 0xFFFF0000u;
        const float lf = x - __uint_as_float(uh);       // exact residual
        wsp[base + j]        = (unsigned short)(u >> 16);
        wsp[4096 + base + j] = (unsigned short)(__float_as_uint(lf) >> 16);
    }
}

// 256 threads = 4 waves = 2 batch elems; each elem split across 2 waves.
// 8192 waves total -> 32 waves/CU possible (vs 16 before): latency hiding 2x.
__global__ __launch_bounds__(256, 8)   // cap 64 VGPR -> 8 waves/SIMD
void kgs_kernel(const int* __restrict__ u, const int* __restrict__ v,
                const int* __restrict__ adj, const int* __restrict__ rel_adj,
                const float* __restrict__ usr_emb, const float* __restrict__ ent_emb,
                const float* __restrict__ rel_emb,
                const float* __restrict__ W0, const float* __restrict__ b0,
                const float* __restrict__ W1, const float* __restrict__ b1,
                const unsigned short* __restrict__ wsp,
                float* __restrict__ out, int B)
{
    const int tid = threadIdx.x;
    const int wid = tid >> 6;            // 0..3
    const int b_l = wid >> 1;            // pair slot in block (0,1)
    const int h   = wid & 1;             // half: which 8 hop-1 neighbors
    const int d   = tid & 63;
    int b = blockIdx.x * 2 + b_l;
    if (b >= B) b = B - 1;
    const int n16 = d & 15;

    __shared__ float ur_sh[4][NREL + 3];            // per-WAVE score tables
    __shared__ __align__(16) float sv_sh[2][NNB * XSTR];   // per-b hop-1 sv rows
    __shared__ __align__(16) float xbuf[2][NNB * XSTR];    // per-b xs tile, reused for h1

    const int uu = u[b];
    const int vv = v[b];

    const float user_d = usr_emb[(size_t)uu * DIMN + d];
    const int e1n = adj[vv * NNB + n16];
    const int r1n = rel_adj[vv * NNB + n16];
    const float sv0 = ent_emb[(size_t)vv * DIMN + d];   // prefetch for hop0

    // ---- per-wave ur table straight from global (usr row = broadcast L1 hit);
    //      no LDS dependency, no barrier before phase B
    if (d < NREL) {
        const float* up = usr_emb + (size_t)uu * DIMN;
        const float* re = rel_emb + d * DIMN;
        float acc = 0.f;
        #pragma unroll
        for (int k = 0; k < DIMN; k += 4) {
            const float4 uk = *(const float4*)(up + k);
            const float4 rk = *(const float4*)(re + k);
            acc = fmaf(uk.x, rk.x, acc);
            acc = fmaf(uk.y, rk.y, acc);
            acc = fmaf(uk.z, rk.z, acc);
            acc = fmaf(uk.w, rk.w, acc);
        }
        ur_sh[wid][d] = acc;
    }

    // ================= phase B: this wave's 8 hop-1 neighbors =================
    float sv_r[MH];
    int   e2n_r[MH], r2n_r[MH];
    #pragma unroll
    for (int mi = 0; mi < MH; ++mi) {
        const int m  = h * MH + mi;
        const int em = __builtin_amdgcn_readlane(e1n, m);
        sv_r[mi]  = ent_emb[(size_t)em * DIMN + d];
        e2n_r[mi] = adj[em * NNB + n16];
        r2n_r[mi] = rel_adj[em * NNB + n16];
    }

    float attn[MH];
    #pragma unroll
    for (int mi = 0; mi < MH; ++mi) {
        const float e = __expf(ur_sh[wid][r2n_r[mi]]);
        float s = e;
        s += __shfl_xor(s, 1);
        s += __shfl_xor(s, 2);
        s += __shfl_xor(s, 4);
        s += __shfl_xor(s, 8);
        attn[mi] = e * __builtin_amdgcn_rcpf(s);
    }

    float agg[MH];
    #pragma unroll
    for (int mi = 0; mi < MH; ++mi) agg[mi] = 0.f;
    #pragma unroll
    for (int mi = 0; mi < MH; ++mi) {
        #pragma unroll
        for (int n = 0; n < NNB; ++n) {
            const int en = __builtin_amdgcn_readlane(e2n_r[mi], n);
            agg[mi] = fmaf(bcastf(attn[mi], n), ent_emb[(size_t)en * DIMN + d], agg[mi]);
        }
    }

    #pragma unroll
    for (int mi = 0; mi < MH; ++mi) {
        const int m = h * MH + mi;
        sv_sh[b_l][m * XSTR + d] = sv_r[mi];
        xbuf[b_l][m * XSTR + d]  = sv_r[mi] + agg[mi];
    }
    __syncthreads();                                   // xs/sv tiles complete

    // ---- A-fragments from the FULL 16-row xs tile (both waves of pair read it)
    shortx8 Ahi[2], Alo[2];
    #pragma unroll
    for (int ks = 0; ks < 2; ++ks) {
        const float* ar = &xbuf[b_l][(d & 15) * XSTR + ((d >> 4) * 8) + ks * 32];
        const floatx4 xa = *(const floatx4*)ar;
        const floatx4 xb = *(const floatx4*)(ar + 4);
        unsigned uh[8], ul[8];
        #pragma unroll
        for (int j = 0; j < 8; ++j) {
            const float x = (j < 4) ? xa[j] : xb[j - 4];
            const unsigned ub = __float_as_uint(x);
            uh[j] = ub & 0xFFFF0000u;
            ul[j] = __float_as_uint(x - __uint_as_float(uh[j]));
        }
        union { int i[4]; shortx8 s; } ch, cl;
        #pragma unroll
        for (int p = 0; p < 4; ++p) {
            ch.i[p] = (int)(uh[2 * p + 1] | (uh[2 * p] >> 16));
            cl.i[p] = (int)((ul[2 * p + 1] & 0xFFFF0000u) | (ul[2 * p] >> 16));
        }
        Ahi[ks] = ch.s;
        Alo[ks] = cl.s;
    }

    // ---- MFMA, split by N col-block: this wave does t = 2h, 2h+1 (12 MFMAs)
    const shortx8* wf = (const shortx8*)wsp;
    floatx4 acc[2];
    #pragma unroll
    for (int tt = 0; tt < 2; ++tt) acc[tt] = (floatx4){0.f, 0.f, 0.f, 0.f};
    #pragma unroll
    for (int tt = 0; tt < 2; ++tt) {
        const int t = 2 * h + tt;
        #pragma unroll
        for (int ks = 0; ks < 2; ++ks) {
            const int f = ks * 4 + t;
            const shortx8 bhi = wf[f * 64 + d];
            const shortx8 blo = wf[512 + f * 64 + d];
            acc[tt] = __builtin_amdgcn_mfma_f32_16x16x32_bf16(Ahi[ks], bhi, acc[tt], 0, 0, 0);
            acc[tt] = __builtin_amdgcn_mfma_f32_16x16x32_bf16(Ahi[ks], blo, acc[tt], 0, 0, 0);
            acc[tt] = __builtin_amdgcn_mfma_f32_16x16x32_bf16(Alo[ks], bhi, acc[tt], 0, 0, 0);
        }
    }
    __syncthreads();                                   // A-frag reads done -> safe to overwrite

    // ---- bias + sigmoid, write h1 col-blocks (D: row=(d>>4)*4+reg, col=t*16+(d&15))
    #pragma unroll
    for (int tt = 0; tt < 2; ++tt) {
        const int t = 2 * h + tt;
        const float bv = b0[t * 16 + (d & 15)];
        #pragma unroll
        for (int reg = 0; reg < 4; ++reg) {
            const float o = acc[tt][reg] + bv;
            const int m = (d >> 4) * 4 + reg;
            xbuf[b_l][m * XSTR + t * 16 + (d & 15)] = 1.f / (1.f + __expf(-o));
        }
    }
    __syncthreads();                                   // h1 complete

    if (h == 1) return;                                // wave 1 done; wave 0 runs epilogue

    // ================= hop-0 (wave 0 of each pair) ============================
    const float e0 = __expf(ur_sh[wid][r1n]);
    float sum0 = e0;
    sum0 += __shfl_xor(sum0, 1);
    sum0 += __shfl_xor(sum0, 2);
    sum0 += __shfl_xor(sum0, 4);
    sum0 += __shfl_xor(sum0, 8);
    const float attn0 = e0 * __builtin_amdgcn_rcpf(sum0);

    float agg0 = 0.f, agg1 = 0.f;
    #pragma unroll
    for (int n = 0; n < NNB; ++n) {
        const float an = bcastf(attn0, n);
        agg0 = fmaf(an, sv_sh[b_l][n * XSTR + d], agg0);
        agg1 = fmaf(an, xbuf[b_l][n * XSTR + d], agg1);
    }

    // ---- iter0/hop0: sigmoid((sv0+agg0) @ W0 + b0)
    const float x0 = sv0 + agg0;
    float a0 = 0.f, a1 = 0.f, a2 = 0.f, a3 = 0.f;
    for (int k = 0; k < DIMN; k += 4) {
        const float* wr = W0 + k * DIMN;
        a0 = fmaf(bcastf(x0, k + 0), wr[d], a0);
        a1 = fmaf(bcastf(x0, k + 1), wr[DIMN + d], a1);
        a2 = fmaf(bcastf(x0, k + 2), wr[2 * DIMN + d], a2);
        a3 = fmaf(bcastf(x0, k + 3), wr[3 * DIMN + d], a3);
    }
    const float o0 = b0[d] + ((a0 + a1) + (a2 + a3));
    const float h0 = 1.f / (1.f + __expf(-o0));

    // ---- iter1/hop0: tanh((h0+agg1) @ W1 + b1)
    const float x1 = h0 + agg1;
    float c0 = 0.f, c1 = 0.f, c2 = 0.f, c3 = 0.f;
    for (int k = 0; k < DIMN; k += 4) {
        const float* wr = W1 + k * DIMN;
        c0 = fmaf(bcastf(x1, k + 0), wr[d], c0);
        c1 = fmaf(bcastf(x1, k + 1), wr[DIMN + d], c1);
        c2 = fmaf(bcastf(x1, k + 2), wr[2 * DIMN + d], c2);
        c3 = fmaf(bcastf(x1, k + 3), wr[3 * DIMN + d], c3);
    }
    const float o1 = b1[d] + ((c0 + c1) + (c2 + c3));
    const float item_d = 1.f - 2.f / (1.f + __expf(2.f * o1));  // tanh

    // ---- final: sigmoid(user . item)
    float p = user_d * item_d;
    p += __shfl_xor(p, 1);
    p += __shfl_xor(p, 2);
    p += __shfl_xor(p, 4);
    p += __shfl_xor(p, 8);
    p += __shfl_xor(p, 16);
    p += __shfl_xor(p, 32);
    if (d == 0) out[b] = 1.f / (1.f + __expf(-p));
}

extern "C" void kernel_launch(void* const* d_in, const int* in_sizes, int n_in,
                              void* d_out, int out_size, void* d_ws, size_t ws_size,
                              hipStream_t stream) {
    const int*   u       = (const int*)d_in[0];
    const int*   v       = (const int*)d_in[1];
    const int*   adj     = (const int*)d_in[2];
    const int*   rel_adj = (const int*)d_in[3];
    const float* usr_emb = (const float*)d_in[4];
    const float* ent_emb = (const float*)d_in[5];
    const float* rel_emb = (const float*)d_in[6];
    const float* W0      = (const float*)d_in[7];
    const float* b0      = (const float*)d_in[8];
    const float* W1      = (const float*)d_in[9];
    const float* b1      = (const float*)d_in[10];
    float* out = (float*)d_out;
    unsigned short* wsp = (unsigned short*)d_ws;

    const int B = in_sizes[0];   // 4096
    prep_w0_frags<<<dim3(2), dim3(256), 0, stream>>>(W0, wsp);
    const int grid = (B + 1) / 2;
    kgs_kernel<<<dim3(grid), dim3(256), 0, stream>>>(u, v, adj, rel_adj, usr_emb,
                                                     ent_emb, rel_emb, W0, b0, W1, b1,
                                                     wsp, out, B);
}

// Round 5
// 167.427 us; speedup vs baseline: 1.1179x; 1.1179x over previous
//
#include <hip/hip_runtime.h>

#define DIMN 64
#define NNB 16
#define NREL 33
#define MH 8           // hop-1 neighbors handled per wave (16 / 2 waves)
#define XSTR 68        // LDS tile row stride in floats (pad: 2-way banks = free)

typedef float  floatx4 __attribute__((ext_vector_type(4)));
typedef short  shortx8 __attribute__((ext_vector_type(8)));

__device__ __forceinline__ float bcastf(float x, int lane) {
    return __int_as_float(__builtin_amdgcn_readlane(__float_as_int(x), lane));
}

// ---- prep: split W0 (fp32 64x64) into bf16 hi/lo MFMA B-fragments in d_ws ----
__global__ void prep_w0_frags(const float* __restrict__ W0, unsigned short* __restrict__ wsp) {
    const int tid = blockIdx.x * blockDim.x + threadIdx.x;   // 0..511
    if (tid >= 512) return;
    const int l = tid & 63;
    const int t = (tid >> 6) & 3;
    const int ks = tid >> 8;
    const int k0 = ks * 32 + (l >> 4) * 8;
    const int n  = t * 16 + (l & 15);
    const unsigned base = ((unsigned)(ks * 4 + t) * 64 + l) * 8;
    #pragma unroll
    for (int j = 0; j < 8; ++j) {
        const float x = W0[(k0 + j) * DIMN + n];
        const unsigned u  = __float_as_uint(x);
        const unsigned uh = u & 0xFFFF0000u;
        const float lf = x - __uint_as_float(uh);       // exact residual
        wsp[base + j]        = (unsigned short)(u >> 16);
        wsp[4096 + base + j] = (unsigned short)(__float_as_uint(lf) >> 16);
    }
}

// 256 threads = 4 waves = 2 batch elems; each elem split across 2 waves.
// launch_bounds(256,6): 85-VGPR budget (MLP!) x 24 waves/CU. Round 4's (256,8)
// squeezed to 32 VGPR -> 6 MB scratch spill + serialized gathers. VGPRs buy MLP;
// MLP > occupancy here.
__global__ __launch_bounds__(256, 6)
void kgs_kernel(const int* __restrict__ u, const int* __restrict__ v,
                const int* __restrict__ adj, const int* __restrict__ rel_adj,
                const float* __restrict__ usr_emb, const float* __restrict__ ent_emb,
                const float* __restrict__ rel_emb,
                const float* __restrict__ W0, const float* __restrict__ b0,
                const float* __restrict__ W1, const float* __restrict__ b1,
                const unsigned short* __restrict__ wsp,
                float* __restrict__ out, int B)
{
    const int tid = threadIdx.x;
    const int wid = tid >> 6;            // 0..3
    const int b_l = wid >> 1;            // pair slot in block (0,1)
    const int h   = wid & 1;             // half: which 8 hop-1 neighbors
    const int d   = tid & 63;
    int b = blockIdx.x * 2 + b_l;
    if (b >= B) b = B - 1;
    const int n16 = d & 15;

    __shared__ float ur_sh[4][NREL + 3];                   // per-WAVE score tables
    __shared__ __align__(16) float sv_sh[2][NNB * XSTR];   // per-b hop-1 sv rows
    __shared__ __align__(16) float xbuf[2][NNB * XSTR];    // per-b xs tile, reused for h1

    const int uu = u[b];
    const int vv = v[b];

    const float user_d = usr_emb[(size_t)uu * DIMN + d];
    const int e1n = adj[vv * NNB + n16];
    const int r1n = rel_adj[vv * NNB + n16];
    const float sv0 = ent_emb[(size_t)vv * DIMN + d];   // prefetch for hop0

    // ---- per-wave ur table straight from global (usr row = broadcast L1 hit);
    //      no LDS dependency, no barrier before phase B
    if (d < NREL) {
        const float* up = usr_emb + (size_t)uu * DIMN;
        const float* re = rel_emb + d * DIMN;
        float acc = 0.f;
        #pragma unroll
        for (int k = 0; k < DIMN; k += 4) {
            const float4 uk = *(const float4*)(up + k);
            const float4 rk = *(const float4*)(re + k);
            acc = fmaf(uk.x, rk.x, acc);
            acc = fmaf(uk.y, rk.y, acc);
            acc = fmaf(uk.z, rk.z, acc);
            acc = fmaf(uk.w, rk.w, acc);
        }
        ur_sh[wid][d] = acc;
    }

    // ================= phase B: this wave's 8 hop-1 neighbors =================
    float sv_r[MH];
    int   e2n_r[MH], r2n_r[MH];
    #pragma unroll
    for (int mi = 0; mi < MH; ++mi) {
        const int m  = h * MH + mi;
        const int em = __builtin_amdgcn_readlane(e1n, m);
        sv_r[mi]  = ent_emb[(size_t)em * DIMN + d];
        e2n_r[mi] = adj[em * NNB + n16];
        r2n_r[mi] = rel_adj[em * NNB + n16];
    }

    float attn[MH];
    #pragma unroll
    for (int mi = 0; mi < MH; ++mi) {
        const float e = __expf(ur_sh[wid][r2n_r[mi]]);
        float s = e;
        s += __shfl_xor(s, 1);
        s += __shfl_xor(s, 2);
        s += __shfl_xor(s, 4);
        s += __shfl_xor(s, 8);
        attn[mi] = e * __builtin_amdgcn_rcpf(s);
    }

    // ---- hop-2 gather: batch-then-reduce. All 16 loads of one mi issue into
    //      g[16] BEFORE any consumption -> 16 loads in flight per mi, and the
    //      compiler can overlap mi+1's loads with mi's reduction.
    float agg[MH];
    #pragma unroll
    for (int mi = 0; mi < MH; ++mi) {
        float g[NNB];
        #pragma unroll
        for (int n = 0; n < NNB; ++n) {
            const int en = __builtin_amdgcn_readlane(e2n_r[mi], n);  // SGPR
            g[n] = ent_emb[(size_t)en * DIMN + d];                   // sgpr-base + d
        }
        float p0 = 0.f, p1 = 0.f, p2 = 0.f, p3 = 0.f;
        #pragma unroll
        for (int n = 0; n < NNB; n += 4) {
            p0 = fmaf(bcastf(attn[mi], n + 0), g[n + 0], p0);
            p1 = fmaf(bcastf(attn[mi], n + 1), g[n + 1], p1);
            p2 = fmaf(bcastf(attn[mi], n + 2), g[n + 2], p2);
            p3 = fmaf(bcastf(attn[mi], n + 3), g[n + 3], p3);
        }
        agg[mi] = (p0 + p1) + (p2 + p3);
    }

    #pragma unroll
    for (int mi = 0; mi < MH; ++mi) {
        const int m = h * MH + mi;
        sv_sh[b_l][m * XSTR + d] = sv_r[mi];
        xbuf[b_l][m * XSTR + d]  = sv_r[mi] + agg[mi];
    }
    __syncthreads();                                   // xs/sv tiles complete

    // ---- A-fragments from the FULL 16-row xs tile (both waves of pair read it)
    shortx8 Ahi[2], Alo[2];
    #pragma unroll
    for (int ks = 0; ks < 2; ++ks) {
        const float* ar = &xbuf[b_l][(d & 15) * XSTR + ((d >> 4) * 8) + ks * 32];
        const floatx4 xa = *(const floatx4*)ar;
        const floatx4 xb = *(const floatx4*)(ar + 4);
        unsigned uh[8], ul[8];
        #pragma unroll
        for (int j = 0; j < 8; ++j) {
            const float x = (j < 4) ? xa[j] : xb[j - 4];
            const unsigned ub = __float_as_uint(x);
            uh[j] = ub & 0xFFFF0000u;
            ul[j] = __float_as_uint(x - __uint_as_float(uh[j]));
        }
        union { int i[4]; shortx8 s; } ch, cl;
        #pragma unroll
        for (int p = 0; p < 4; ++p) {
            ch.i[p] = (int)(uh[2 * p + 1] | (uh[2 * p] >> 16));
            cl.i[p] = (int)((ul[2 * p + 1] & 0xFFFF0000u) | (ul[2 * p] >> 16));
        }
        Ahi[ks] = ch.s;
        Alo[ks] = cl.s;
    }

    // ---- MFMA, split by N col-block: this wave does t = 2h, 2h+1 (12 MFMAs)
    const shortx8* wf = (const shortx8*)wsp;
    floatx4 acc[2];
    #pragma unroll
    for (int tt = 0; tt < 2; ++tt) acc[tt] = (floatx4){0.f, 0.f, 0.f, 0.f};
    #pragma unroll
    for (int tt = 0; tt < 2; ++tt) {
        const int t = 2 * h + tt;
        #pragma unroll
        for (int ks = 0; ks < 2; ++ks) {
            const int f = ks * 4 + t;
            const shortx8 bhi = wf[f * 64 + d];
            const shortx8 blo = wf[512 + f * 64 + d];
            acc[tt] = __builtin_amdgcn_mfma_f32_16x16x32_bf16(Ahi[ks], bhi, acc[tt], 0, 0, 0);
            acc[tt] = __builtin_amdgcn_mfma_f32_16x16x32_bf16(Ahi[ks], blo, acc[tt], 0, 0, 0);
            acc[tt] = __builtin_amdgcn_mfma_f32_16x16x32_bf16(Alo[ks], bhi, acc[tt], 0, 0, 0);
        }
    }
    __syncthreads();                                   // A-frag reads done -> safe to overwrite

    // ---- bias + sigmoid, write h1 col-blocks (D: row=(d>>4)*4+reg, col=t*16+(d&15))
    #pragma unroll
    for (int tt = 0; tt < 2; ++tt) {
        const int t = 2 * h + tt;
        const float bv = b0[t * 16 + (d & 15)];
        #pragma unroll
        for (int reg = 0; reg < 4; ++reg) {
            const float o = acc[tt][reg] + bv;
            const int m = (d >> 4) * 4 + reg;
            xbuf[b_l][m * XSTR + t * 16 + (d & 15)] = 1.f / (1.f + __expf(-o));
        }
    }
    __syncthreads();                                   // h1 complete

    if (h == 1) return;                                // wave 1 done; wave 0 runs epilogue

    // ================= hop-0 (wave 0 of each pair) ============================
    const float e0 = __expf(ur_sh[wid][r1n]);
    float sum0 = e0;
    sum0 += __shfl_xor(sum0, 1);
    sum0 += __shfl_xor(sum0, 2);
    sum0 += __shfl_xor(sum0, 4);
    sum0 += __shfl_xor(sum0, 8);
    const float attn0 = e0 * __builtin_amdgcn_rcpf(sum0);

    float agg0 = 0.f, agg1 = 0.f;
    #pragma unroll
    for (int n = 0; n < NNB; ++n) {
        const float an = bcastf(attn0, n);
        agg0 = fmaf(an, sv_sh[b_l][n * XSTR + d], agg0);
        agg1 = fmaf(an, xbuf[b_l][n * XSTR + d], agg1);
    }

    // ---- iter0/hop0: sigmoid((sv0+agg0) @ W0 + b0)
    const float x0 = sv0 + agg0;
    float a0 = 0.f, a1 = 0.f, a2 = 0.f, a3 = 0.f;
    for (int k = 0; k < DIMN; k += 4) {
        const float* wr = W0 + k * DIMN;
        a0 = fmaf(bcastf(x0, k + 0), wr[d], a0);
        a1 = fmaf(bcastf(x0, k + 1), wr[DIMN + d], a1);
        a2 = fmaf(bcastf(x0, k + 2), wr[2 * DIMN + d], a2);
        a3 = fmaf(bcastf(x0, k + 3), wr[3 * DIMN + d], a3);
    }
    const float o0 = b0[d] + ((a0 + a1) + (a2 + a3));
    const float h0 = 1.f / (1.f + __expf(-o0));

    // ---- iter1/hop0: tanh((h0+agg1) @ W1 + b1)
    const float x1 = h0 + agg1;
    float c0 = 0.f, c1 = 0.f, c2 = 0.f, c3 = 0.f;
    for (int k = 0; k < DIMN; k += 4) {
        const float* wr = W1 + k * DIMN;
        c0 = fmaf(bcastf(x1, k + 0), wr[d], c0);
        c1 = fmaf(bcastf(x1, k + 1), wr[DIMN + d], c1);
        c2 = fmaf(bcastf(x1, k + 2), wr[2 * DIMN + d], c2);
        c3 = fmaf(bcastf(x1, k + 3), wr[3 * DIMN + d], c3);
    }
    const float o1 = b1[d] + ((c0 + c1) + (c2 + c3));
    const float item_d = 1.f - 2.f / (1.f + __expf(2.f * o1));  // tanh

    // ---- final: sigmoid(user . item)
    float p = user_d * item_d;
    p += __shfl_xor(p, 1);
    p += __shfl_xor(p, 2);
    p += __shfl_xor(p, 4);
    p += __shfl_xor(p, 8);
    p += __shfl_xor(p, 16);
    p += __shfl_xor(p, 32);
    if (d == 0) out[b] = 1.f / (1.f + __expf(-p));
}

extern "C" void kernel_launch(void* const* d_in, const int* in_sizes, int n_in,
                              void* d_out, int out_size, void* d_ws, size_t ws_size,
                              hipStream_t stream) {
    const int*   u       = (const int*)d_in[0];
    const int*   v       = (const int*)d_in[1];
    const int*   adj     = (const int*)d_in[2];
    const int*   rel_adj = (const int*)d_in[3];
    const float* usr_emb = (const float*)d_in[4];
    const float* ent_emb = (const float*)d_in[5];
    const float* rel_emb = (const float*)d_in[6];
    const float* W0      = (const float*)d_in[7];
    const float* b0      = (const float*)d_in[8];
    const float* W1      = (const float*)d_in[9];
    const float* b1      = (const float*)d_in[10];
    float* out = (float*)d_out;
    unsigned short* wsp = (unsigned short*)d_ws;

    const int B = in_sizes[0];   // 4096
    prep_w0_frags<<<dim3(2), dim3(256), 0, stream>>>(W0, wsp);
    const int grid = (B + 1) / 2;
    kgs_kernel<<<dim3(grid), dim3(256), 0, stream>>>(u, v, adj, rel_adj, usr_emb,
                                                     ent_emb, rel_emb, W0, b0, W1, b1,
                                                     wsp, out, B);
}

// Round 6
// 160.682 us; speedup vs baseline: 1.1648x; 1.0420x over previous
//
#include <hip/hip_runtime.h>

#define DIMN 64
#define NNB 16
#define NREL 33
#define WPB 4          // batch elements (waves) per block, 1 elem per wave
#define XSTR 68        // LDS tile row stride in floats (68%32=4 -> 2-way banks = free)

typedef float  floatx4 __attribute__((ext_vector_type(4)));
typedef short  shortx8 __attribute__((ext_vector_type(8)));

__device__ __forceinline__ float bcastf(float x, int lane) {
    return __int_as_float(__builtin_amdgcn_readlane(__float_as_int(x), lane));
}

// ---- prep: split W0 (fp32 64x64) into bf16 hi/lo MFMA B-fragments in d_ws ----
__global__ void prep_w0_frags(const float* __restrict__ W0, unsigned short* __restrict__ wsp) {
    const int tid = blockIdx.x * blockDim.x + threadIdx.x;   // 0..511
    if (tid >= 512) return;
    const int l = tid & 63;
    const int t = (tid >> 6) & 3;
    const int ks = tid >> 8;
    const int k0 = ks * 32 + (l >> 4) * 8;
    const int n  = t * 16 + (l & 15);
    const unsigned base = ((unsigned)(ks * 4 + t) * 64 + l) * 8;
    #pragma unroll
    for (int j = 0; j < 8; ++j) {
        const float x = W0[(k0 + j) * DIMN + n];
        const unsigned u  = __float_as_uint(x);
        const unsigned uh = u & 0xFFFF0000u;
        const float lf = x - __uint_as_float(uh);       // exact residual
        wsp[base + j]        = (unsigned short)(u >> 16);
        wsp[4096 + base + j] = (unsigned short)(__float_as_uint(lf) >> 16);
    }
}

// Round-3 structure (zero barriers, wave-private LDS) + VECTORIZED gathers:
// one global_load_dwordx4 covers 4 embedding rows (16 lanes x float4 each)
// -> 4x fewer gather instructions; latency ceases to bind (Little's law).
__global__ __launch_bounds__(64 * WPB, 4)
void kgs_kernel(const int* __restrict__ u, const int* __restrict__ v,
                const int* __restrict__ adj, const int* __restrict__ rel_adj,
                const float* __restrict__ usr_emb, const float* __restrict__ ent_emb,
                const float* __restrict__ rel_emb,
                const float* __restrict__ W0, const float* __restrict__ b0,
                const float* __restrict__ W1, const float* __restrict__ b1,
                const unsigned short* __restrict__ wsp,
                float* __restrict__ out, int B)
{
    const int tid  = threadIdx.x;
    const int wid  = tid >> 6;
    const int d    = tid & 63;
    const int n16  = d & 15;
    const int quad = d >> 4;
    int b = blockIdx.x * WPB + wid;
    if (b >= B) b = B - 1;

    // all LDS wave-private -> no __syncthreads anywhere
    __shared__ __align__(16) float user_sh[WPB][DIMN];
    __shared__ float ur_sh[WPB][NREL + 3];
    __shared__ __align__(16) float sv_sh[WPB][NNB * XSTR];  // hop-1 sv rows
    __shared__ __align__(16) float gbuf[WPB][NNB * XSTR];   // agg rows, then h1

    const int uu = u[b];
    const int vv = v[b];

    const float user_d = usr_emb[(size_t)uu * DIMN + d];
    const int e1n = adj[vv * NNB + n16];
    const int r1n = rel_adj[vv * NNB + n16];
    const float sv0 = ent_emb[(size_t)vv * DIMN + d];
    user_sh[wid][d] = user_d;

    // ---- sv tile: 4 dwordx4 loads cover all 16 hop-1 rows (split layout)
    floatx4 svv[4];
    #pragma unroll
    for (int q = 0; q < 4; ++q) {
        const int em = __shfl(e1n, 4 * q + quad);           // row id for this lane
        svv[q] = *(const floatx4*)(ent_emb + (size_t)em * DIMN + 4 * n16);
    }

    // ---- index prefetch for hop-2 (scalar-base dword loads, small rows)
    int e2n_r[NNB], r2n_r[NNB];
    #pragma unroll
    for (int m = 0; m < NNB; ++m) {
        const int em = __builtin_amdgcn_readlane(e1n, m);
        e2n_r[m] = adj[em * NNB + n16];
        r2n_r[m] = rel_adj[em * NNB + n16];
    }

    // ---- ur table: 33 user-rel dots (wave-private, same-wave LDS)
    if (d < NREL) {
        const float* re = rel_emb + d * DIMN;
        float acc = 0.f;
        #pragma unroll
        for (int k = 0; k < DIMN; k += 4) {
            const float4 uk = *(const float4*)(&user_sh[wid][k]);
            const float4 rk = *(const float4*)(re + k);
            acc = fmaf(uk.x, rk.x, acc);
            acc = fmaf(uk.y, rk.y, acc);
            acc = fmaf(uk.z, rk.z, acc);
            acc = fmaf(uk.w, rk.w, acc);
        }
        ur_sh[wid][d] = acc;
    }

    // park sv tile in LDS (b128 writes, 4 rows per instr)
    #pragma unroll
    for (int q = 0; q < 4; ++q)
        *(floatx4*)(&sv_sh[wid][(4 * q + quad) * XSTR + 4 * n16]) = svv[q];

    // ---- softmax attention for all 16 hop-1 groups (lane layout n16)
    float attn[NNB];
    #pragma unroll
    for (int m = 0; m < NNB; ++m) {
        const float e = __expf(ur_sh[wid][r2n_r[m]]);
        float s = e;
        s += __shfl_xor(s, 1);
        s += __shfl_xor(s, 2);
        s += __shfl_xor(s, 4);
        s += __shfl_xor(s, 8);
        attn[m] = e * __builtin_amdgcn_rcpf(s);
    }

    // ---- hop-2 gather+aggregate, VECTORIZED:
    //      load q covers rows n=4q+quad as float4 (cols 4*n16..); weighted
    //      per-lane fma; cross-quad reduce; lanes<16 write row m as b128.
    #pragma unroll
    for (int m = 0; m < NNB; ++m) {
        floatx4 acc4 = (floatx4){0.f, 0.f, 0.f, 0.f};
        #pragma unroll
        for (int q = 0; q < 4; ++q) {
            const int src = 4 * q + quad;
            const int en  = __shfl(e2n_r[m], src);          // row id (VGPR)
            const floatx4 g = *(const floatx4*)(ent_emb + (size_t)en * DIMN + 4 * n16);
            const float aw = __shfl(attn[m], src);          // weight for that row
            acc4[0] = fmaf(aw, g[0], acc4[0]);
            acc4[1] = fmaf(aw, g[1], acc4[1]);
            acc4[2] = fmaf(aw, g[2], acc4[2]);
            acc4[3] = fmaf(aw, g[3], acc4[3]);
        }
        #pragma unroll
        for (int c = 0; c < 4; ++c) {                       // reduce over quads
            acc4[c] += __shfl_xor(acc4[c], 16);
            acc4[c] += __shfl_xor(acc4[c], 32);
        }
        if (d < 16)
            *(floatx4*)(&gbuf[wid][m * XSTR + 4 * d]) = acc4;
    }

    // ---- A-fragments: xs = sv + agg read from the two tiles; bf16 hi/lo split
    shortx8 Ahi[2], Alo[2];
    #pragma unroll
    for (int ks = 0; ks < 2; ++ks) {
        const int off = (d & 15) * XSTR + quad * 8 + ks * 32;
        const floatx4 sa = *(const floatx4*)(&sv_sh[wid][off]);
        const floatx4 sb = *(const floatx4*)(&sv_sh[wid][off + 4]);
        const floatx4 ga = *(const floatx4*)(&gbuf[wid][off]);
        const floatx4 gb = *(const floatx4*)(&gbuf[wid][off + 4]);
        unsigned uh[8], ul[8];
        #pragma unroll
        for (int j = 0; j < 8; ++j) {
            const float x = (j < 4) ? (sa[j] + ga[j]) : (sb[j - 4] + gb[j - 4]);
            const unsigned ub = __float_as_uint(x);
            uh[j] = ub & 0xFFFF0000u;
            ul[j] = __float_as_uint(x - __uint_as_float(uh[j]));
        }
        union { int i[4]; shortx8 s; } ch, cl;
        #pragma unroll
        for (int p = 0; p < 4; ++p) {
            ch.i[p] = (int)(uh[2 * p + 1] | (uh[2 * p] >> 16));
            cl.i[p] = (int)((ul[2 * p + 1] & 0xFFFF0000u) | (ul[2 * p] >> 16));
        }
        Ahi[ks] = ch.s;
        Alo[ks] = cl.s;
    }

    // ---- MFMA: O = Xhi*Whi + Xhi*Wlo + Xlo*Whi (fp32-accurate 3-term)
    const shortx8* wf = (const shortx8*)wsp;
    floatx4 acc[4];
    #pragma unroll
    for (int t = 0; t < 4; ++t) acc[t] = (floatx4){0.f, 0.f, 0.f, 0.f};
    #pragma unroll
    for (int t = 0; t < 4; ++t) {
        #pragma unroll
        for (int ks = 0; ks < 2; ++ks) {
            const int f = ks * 4 + t;
            const shortx8 bhi = wf[f * 64 + d];
            const shortx8 blo = wf[512 + f * 64 + d];
            acc[t] = __builtin_amdgcn_mfma_f32_16x16x32_bf16(Ahi[ks], bhi, acc[t], 0, 0, 0);
            acc[t] = __builtin_amdgcn_mfma_f32_16x16x32_bf16(Ahi[ks], blo, acc[t], 0, 0, 0);
            acc[t] = __builtin_amdgcn_mfma_f32_16x16x32_bf16(Alo[ks], bhi, acc[t], 0, 0, 0);
        }
    }

    // ---- bias + sigmoid in D-layout (row=quad*4+reg, col=t*16+n16) -> gbuf (reuse)
    #pragma unroll
    for (int t = 0; t < 4; ++t) {
        const float bv = b0[t * 16 + n16];
        #pragma unroll
        for (int reg = 0; reg < 4; ++reg) {
            const float o = acc[t][reg] + bv;
            const int m = quad * 4 + reg;
            gbuf[wid][m * XSTR + t * 16 + n16] = 1.f / (1.f + __expf(-o));
        }
    }

    // ================= hop-0 (per wave, own elem) =============================
    const float e0 = __expf(ur_sh[wid][r1n]);
    float sum0 = e0;
    sum0 += __shfl_xor(sum0, 1);
    sum0 += __shfl_xor(sum0, 2);
    sum0 += __shfl_xor(sum0, 4);
    sum0 += __shfl_xor(sum0, 8);
    const float attn0 = e0 * __builtin_amdgcn_rcpf(sum0);

    float agg0 = 0.f, agg1 = 0.f;
    #pragma unroll
    for (int n = 0; n < NNB; ++n) {
        const float an = bcastf(attn0, n);
        agg0 = fmaf(an, sv_sh[wid][n * XSTR + d], agg0);
        agg1 = fmaf(an, gbuf[wid][n * XSTR + d], agg1);
    }

    // ---- iter0/hop0: sigmoid((sv0+agg0) @ W0 + b0)
    const float x0 = sv0 + agg0;
    float a0 = 0.f, a1 = 0.f, a2 = 0.f, a3 = 0.f;
    for (int k = 0; k < DIMN; k += 4) {
        const float* wr = W0 + k * DIMN;
        a0 = fmaf(bcastf(x0, k + 0), wr[d], a0);
        a1 = fmaf(bcastf(x0, k + 1), wr[DIMN + d], a1);
        a2 = fmaf(bcastf(x0, k + 2), wr[2 * DIMN + d], a2);
        a3 = fmaf(bcastf(x0, k + 3), wr[3 * DIMN + d], a3);
    }
    const float o0 = b0[d] + ((a0 + a1) + (a2 + a3));
    const float h0 = 1.f / (1.f + __expf(-o0));

    // ---- iter1/hop0: tanh((h0+agg1) @ W1 + b1)
    const float x1 = h0 + agg1;
    float c0 = 0.f, c1 = 0.f, c2 = 0.f, c3 = 0.f;
    for (int k = 0; k < DIMN; k += 4) {
        const float* wr = W1 + k * DIMN;
        c0 = fmaf(bcastf(x1, k + 0), wr[d], c0);
        c1 = fmaf(bcastf(x1, k + 1), wr[DIMN + d], c1);
        c2 = fmaf(bcastf(x1, k + 2), wr[2 * DIMN + d], c2);
        c3 = fmaf(bcastf(x1, k + 3), wr[3 * DIMN + d], c3);
    }
    const float o1 = b1[d] + ((c0 + c1) + (c2 + c3));
    const float item_d = 1.f - 2.f / (1.f + __expf(2.f * o1));  // tanh

    // ---- final: sigmoid(user . item)
    float p = user_d * item_d;
    p += __shfl_xor(p, 1);
    p += __shfl_xor(p, 2);
    p += __shfl_xor(p, 4);
    p += __shfl_xor(p, 8);
    p += __shfl_xor(p, 16);
    p += __shfl_xor(p, 32);
    if (d == 0) out[b] = 1.f / (1.f + __expf(-p));
}

extern "C" void kernel_launch(void* const* d_in, const int* in_sizes, int n_in,
                              void* d_out, int out_size, void* d_ws, size_t ws_size,
                              hipStream_t stream) {
    const int*   u       = (const int*)d_in[0];
    const int*   v       = (const int*)d_in[1];
    const int*   adj     = (const int*)d_in[2];
    const int*   rel_adj = (const int*)d_in[3];
    const float* usr_emb = (const float*)d_in[4];
    const float* ent_emb = (const float*)d_in[5];
    const float* rel_emb = (const float*)d_in[6];
    const float* W0      = (const float*)d_in[7];
    const float* b0      = (const float*)d_in[8];
    const float* W1      = (const float*)d_in[9];
    const float* b1      = (const float*)d_in[10];
    float* out = (float*)d_out;
    unsigned short* wsp = (unsigned short*)d_ws;

    const int B = in_sizes[0];   // 4096
    prep_w0_frags<<<dim3(2), dim3(256), 0, stream>>>(W0, wsp);
    const int grid = (B + WPB - 1) / WPB;
    kgs_kernel<<<dim3(grid), dim3(64 * WPB), 0, stream>>>(u, v, adj, rel_adj, usr_emb,
                                                          ent_emb, rel_emb, W0, b0, W1, b1,
                                                          wsp, out, B);
}

// Round 7
// 156.719 us; speedup vs baseline: 1.1943x; 1.0253x over previous
//
#include <hip/hip_runtime.h>
#include <hip/hip_fp16.h>

#define DIMN 64
#define NNB 16
#define NREL 33
#define WPB 4          // batch elements (waves) per block, 1 elem per wave
#define XSTR 68        // LDS tile row stride in floats (68%32=4 -> 2-way banks = free)
#define WFRAG_BYTES 16384   // w0 hi/lo fragments region at start of d_ws

typedef float        floatx4 __attribute__((ext_vector_type(4)));
typedef short        shortx8 __attribute__((ext_vector_type(8)));
typedef unsigned int uintx2  __attribute__((ext_vector_type(2)));

__device__ __forceinline__ float bcastf(float x, int lane) {
    return __int_as_float(__builtin_amdgcn_readlane(__float_as_int(x), lane));
}

// ---- prep: (a) split W0 into bf16 hi/lo MFMA B-fragments; (b) convert
//      ent_emb fp32 -> fp16 table (halves every gathered row to ONE cache line)
__global__ void prep_kernel(const float* __restrict__ W0, unsigned short* __restrict__ wsp,
                            const float* __restrict__ ent, __half* __restrict__ ent16,
                            long n4)
{
    const long tid = (long)blockIdx.x * blockDim.x + threadIdx.x;
    if (tid < 512) {
        const int l = (int)tid & 63;
        const int t = ((int)tid >> 6) & 3;
        const int ks = (int)tid >> 8;
        const int k0 = ks * 32 + (l >> 4) * 8;
        const int n  = t * 16 + (l & 15);
        const unsigned base = ((unsigned)(ks * 4 + t) * 64 + l) * 8;
        #pragma unroll
        for (int j = 0; j < 8; ++j) {
            const float x = W0[(k0 + j) * DIMN + n];
            const unsigned u  = __float_as_uint(x);
            const unsigned uh = u & 0xFFFF0000u;
            const float lf = x - __uint_as_float(uh);       // exact residual
            wsp[base + j]        = (unsigned short)(u >> 16);
            wsp[4096 + base + j] = (unsigned short)(__float_as_uint(lf) >> 16);
        }
    }
    if (ent16) {
        const long stride = (long)gridDim.x * blockDim.x;
        for (long i = tid; i < n4; i += stride) {           // unit = 4 floats
            const float4 x = ((const float4*)ent)[i];
            __half2 a = __floats2half2_rn(x.x, x.y);
            __half2 b = __floats2half2_rn(x.z, x.w);
            ((__half2*)ent16)[2 * i]     = a;
            ((__half2*)ent16)[2 * i + 1] = b;
        }
    }
}

__device__ __forceinline__ floatx4 cvt4(uintx2 raw) {
    union { unsigned int u; __half2 h; } a, b;
    a.u = raw.x; b.u = raw.y;
    const float2 f01 = __half22float2(a.h);
    const float2 f23 = __half22float2(b.h);
    return (floatx4){f01.x, f01.y, f23.x, f23.y};
}

// Round-6 structure (zero barriers, wave-private LDS, vectorized gathers);
// F16: ent rows read from the fp16 table -> 128 B/row = 1 line (2x less traffic).
template<bool F16>
__global__ __launch_bounds__(64 * WPB, 4)
void kgs_kernel(const int* __restrict__ u, const int* __restrict__ v,
                const int* __restrict__ adj, const int* __restrict__ rel_adj,
                const float* __restrict__ usr_emb, const float* __restrict__ ent_emb,
                const __half* __restrict__ ent16,
                const float* __restrict__ rel_emb,
                const float* __restrict__ W0, const float* __restrict__ b0,
                const float* __restrict__ W1, const float* __restrict__ b1,
                const unsigned short* __restrict__ wsp,
                float* __restrict__ out, int B)
{
    const int tid  = threadIdx.x;
    const int wid  = tid >> 6;
    const int d    = tid & 63;
    const int n16  = d & 15;
    const int quad = d >> 4;
    int b = blockIdx.x * WPB + wid;
    if (b >= B) b = B - 1;

    // all LDS wave-private -> no __syncthreads anywhere
    __shared__ __align__(16) float user_sh[WPB][DIMN];
    __shared__ float ur_sh[WPB][NREL + 3];
    __shared__ __align__(16) float sv_sh[WPB][NNB * XSTR];  // hop-1 sv rows
    __shared__ __align__(16) float gbuf[WPB][NNB * XSTR];   // agg rows, then h1

    const int uu = u[b];
    const int vv = v[b];

    const float user_d = usr_emb[(size_t)uu * DIMN + d];
    const int e1n = adj[vv * NNB + n16];
    const int r1n = rel_adj[vv * NNB + n16];
    float sv0;
    if constexpr (F16) sv0 = __half2float(ent16[(size_t)vv * DIMN + d]);
    else               sv0 = ent_emb[(size_t)vv * DIMN + d];
    user_sh[wid][d] = user_d;

    // ---- sv tile: 4 loads cover all 16 hop-1 rows (split layout)
    floatx4 svv[4];
    #pragma unroll
    for (int q = 0; q < 4; ++q) {
        const int em = __shfl(e1n, 4 * q + quad);           // row id for this lane
        if constexpr (F16)
            svv[q] = cvt4(*(const uintx2*)(ent16 + (size_t)em * DIMN + 4 * n16));
        else
            svv[q] = *(const floatx4*)(ent_emb + (size_t)em * DIMN + 4 * n16);
    }

    // ---- index prefetch for hop-2
    int e2n_r[NNB], r2n_r[NNB];
    #pragma unroll
    for (int m = 0; m < NNB; ++m) {
        const int em = __builtin_amdgcn_readlane(e1n, m);
        e2n_r[m] = adj[em * NNB + n16];
        r2n_r[m] = rel_adj[em * NNB + n16];
    }

    // ---- ur table: 33 user-rel dots (wave-private, same-wave LDS)
    if (d < NREL) {
        const float* re = rel_emb + d * DIMN;
        float acc = 0.f;
        #pragma unroll
        for (int k = 0; k < DIMN; k += 4) {
            const float4 uk = *(const float4*)(&user_sh[wid][k]);
            const float4 rk = *(const float4*)(re + k);
            acc = fmaf(uk.x, rk.x, acc);
            acc = fmaf(uk.y, rk.y, acc);
            acc = fmaf(uk.z, rk.z, acc);
            acc = fmaf(uk.w, rk.w, acc);
        }
        ur_sh[wid][d] = acc;
    }

    // park sv tile in LDS (b128 writes, 4 rows per instr)
    #pragma unroll
    for (int q = 0; q < 4; ++q)
        *(floatx4*)(&sv_sh[wid][(4 * q + quad) * XSTR + 4 * n16]) = svv[q];

    // ---- softmax attention for all 16 hop-1 groups (lane layout n16)
    float attn[NNB];
    #pragma unroll
    for (int m = 0; m < NNB; ++m) {
        const float e = __expf(ur_sh[wid][r2n_r[m]]);
        float s = e;
        s += __shfl_xor(s, 1);
        s += __shfl_xor(s, 2);
        s += __shfl_xor(s, 4);
        s += __shfl_xor(s, 8);
        attn[m] = e * __builtin_amdgcn_rcpf(s);
    }

    // ---- hop-2 gather+aggregate, vectorized (4 rows per load)
    #pragma unroll
    for (int m = 0; m < NNB; ++m) {
        floatx4 acc4 = (floatx4){0.f, 0.f, 0.f, 0.f};
        #pragma unroll
        for (int q = 0; q < 4; ++q) {
            const int src = 4 * q + quad;
            const int en  = __shfl(e2n_r[m], src);          // row id (VGPR)
            floatx4 g;
            if constexpr (F16)
                g = cvt4(*(const uintx2*)(ent16 + (size_t)en * DIMN + 4 * n16));
            else
                g = *(const floatx4*)(ent_emb + (size_t)en * DIMN + 4 * n16);
            const float aw = __shfl(attn[m], src);          // weight for that row
            acc4[0] = fmaf(aw, g[0], acc4[0]);
            acc4[1] = fmaf(aw, g[1], acc4[1]);
            acc4[2] = fmaf(aw, g[2], acc4[2]);
            acc4[3] = fmaf(aw, g[3], acc4[3]);
        }
        #pragma unroll
        for (int c = 0; c < 4; ++c) {                       // reduce over quads
            acc4[c] += __shfl_xor(acc4[c], 16);
            acc4[c] += __shfl_xor(acc4[c], 32);
        }
        if (d < 16)
            *(floatx4*)(&gbuf[wid][m * XSTR + 4 * d]) = acc4;
    }

    // ---- A-fragments: xs = sv + agg; bf16 hi/lo split
    shortx8 Ahi[2], Alo[2];
    #pragma unroll
    for (int ks = 0; ks < 2; ++ks) {
        const int off = (d & 15) * XSTR + quad * 8 + ks * 32;
        const floatx4 sa = *(const floatx4*)(&sv_sh[wid][off]);
        const floatx4 sb = *(const floatx4*)(&sv_sh[wid][off + 4]);
        const floatx4 ga = *(const floatx4*)(&gbuf[wid][off]);
        const floatx4 gb = *(const floatx4*)(&gbuf[wid][off + 4]);
        unsigned uh[8], ul[8];
        #pragma unroll
        for (int j = 0; j < 8; ++j) {
            const float x = (j < 4) ? (sa[j] + ga[j]) : (sb[j - 4] + gb[j - 4]);
            const unsigned ub = __float_as_uint(x);
            uh[j] = ub & 0xFFFF0000u;
            ul[j] = __float_as_uint(x - __uint_as_float(uh[j]));
        }
        union { int i[4]; shortx8 s; } ch, cl;
        #pragma unroll
        for (int p = 0; p < 4; ++p) {
            ch.i[p] = (int)(uh[2 * p + 1] | (uh[2 * p] >> 16));
            cl.i[p] = (int)((ul[2 * p + 1] & 0xFFFF0000u) | (ul[2 * p] >> 16));
        }
        Ahi[ks] = ch.s;
        Alo[ks] = cl.s;
    }

    // ---- MFMA: O = Xhi*Whi + Xhi*Wlo + Xlo*Whi (fp32-accurate 3-term)
    const shortx8* wf = (const shortx8*)wsp;
    floatx4 acc[4];
    #pragma unroll
    for (int t = 0; t < 4; ++t) acc[t] = (floatx4){0.f, 0.f, 0.f, 0.f};
    #pragma unroll
    for (int t = 0; t < 4; ++t) {
        #pragma unroll
        for (int ks = 0; ks < 2; ++ks) {
            const int f = ks * 4 + t;
            const shortx8 bhi = wf[f * 64 + d];
            const shortx8 blo = wf[512 + f * 64 + d];
            acc[t] = __builtin_amdgcn_mfma_f32_16x16x32_bf16(Ahi[ks], bhi, acc[t], 0, 0, 0);
            acc[t] = __builtin_amdgcn_mfma_f32_16x16x32_bf16(Ahi[ks], blo, acc[t], 0, 0, 0);
            acc[t] = __builtin_amdgcn_mfma_f32_16x16x32_bf16(Alo[ks], bhi, acc[t], 0, 0, 0);
        }
    }

    // ---- bias + sigmoid in D-layout (row=quad*4+reg, col=t*16+n16) -> gbuf (reuse)
    #pragma unroll
    for (int t = 0; t < 4; ++t) {
        const float bv = b0[t * 16 + n16];
        #pragma unroll
        for (int reg = 0; reg < 4; ++reg) {
            const float o = acc[t][reg] + bv;
            const int m = quad * 4 + reg;
            gbuf[wid][m * XSTR + t * 16 + n16] = 1.f / (1.f + __expf(-o));
        }
    }

    // ================= hop-0 (per wave, own elem) =============================
    const float e0 = __expf(ur_sh[wid][r1n]);
    float sum0 = e0;
    sum0 += __shfl_xor(sum0, 1);
    sum0 += __shfl_xor(sum0, 2);
    sum0 += __shfl_xor(sum0, 4);
    sum0 += __shfl_xor(sum0, 8);
    const float attn0 = e0 * __builtin_amdgcn_rcpf(sum0);

    float agg0 = 0.f, agg1 = 0.f;
    #pragma unroll
    for (int n = 0; n < NNB; ++n) {
        const float an = bcastf(attn0, n);
        agg0 = fmaf(an, sv_sh[wid][n * XSTR + d], agg0);
        agg1 = fmaf(an, gbuf[wid][n * XSTR + d], agg1);
    }

    // ---- iter0/hop0: sigmoid((sv0+agg0) @ W0 + b0)
    const float x0 = sv0 + agg0;
    float a0 = 0.f, a1 = 0.f, a2 = 0.f, a3 = 0.f;
    for (int k = 0; k < DIMN; k += 4) {
        const float* wr = W0 + k * DIMN;
        a0 = fmaf(bcastf(x0, k + 0), wr[d], a0);
        a1 = fmaf(bcastf(x0, k + 1), wr[DIMN + d], a1);
        a2 = fmaf(bcastf(x0, k + 2), wr[2 * DIMN + d], a2);
        a3 = fmaf(bcastf(x0, k + 3), wr[3 * DIMN + d], a3);
    }
    const float o0 = b0[d] + ((a0 + a1) + (a2 + a3));
    const float h0 = 1.f / (1.f + __expf(-o0));

    // ---- iter1/hop0: tanh((h0+agg1) @ W1 + b1)
    const float x1 = h0 + agg1;
    float c0 = 0.f, c1 = 0.f, c2 = 0.f, c3 = 0.f;
    for (int k = 0; k < DIMN; k += 4) {
        const float* wr = W1 + k * DIMN;
        c0 = fmaf(bcastf(x1, k + 0), wr[d], c0);
        c1 = fmaf(bcastf(x1, k + 1), wr[DIMN + d], c1);
        c2 = fmaf(bcastf(x1, k + 2), wr[2 * DIMN + d], c2);
        c3 = fmaf(bcastf(x1, k + 3), wr[3 * DIMN + d], c3);
    }
    const float o1 = b1[d] + ((c0 + c1) + (c2 + c3));
    const float item_d = 1.f - 2.f / (1.f + __expf(2.f * o1));  // tanh

    // ---- final: sigmoid(user . item)
    float p = user_d * item_d;
    p += __shfl_xor(p, 1);
    p += __shfl_xor(p, 2);
    p += __shfl_xor(p, 4);
    p += __shfl_xor(p, 8);
    p += __shfl_xor(p, 16);
    p += __shfl_xor(p, 32);
    if (d == 0) out[b] = 1.f / (1.f + __expf(-p));
}

extern "C" void kernel_launch(void* const* d_in, const int* in_sizes, int n_in,
                              void* d_out, int out_size, void* d_ws, size_t ws_size,
                              hipStream_t stream) {
    const int*   u       = (const int*)d_in[0];
    const int*   v       = (const int*)d_in[1];
    const int*   adj     = (const int*)d_in[2];
    const int*   rel_adj = (const int*)d_in[3];
    const float* usr_emb = (const float*)d_in[4];
    const float* ent_emb = (const float*)d_in[5];
    const float* rel_emb = (const float*)d_in[6];
    const float* W0      = (const float*)d_in[7];
    const float* b0      = (const float*)d_in[8];
    const float* W1      = (const float*)d_in[9];
    const float* b1      = (const float*)d_in[10];
    float* out = (float*)d_out;
    unsigned short* wsp = (unsigned short*)d_ws;

    const int B = in_sizes[0];                 // 4096
    const long nent = (long)in_sizes[5];       // ent_emb element count (12.8M)
    const size_t need = (size_t)WFRAG_BYTES + (size_t)nent * sizeof(__half);
    const bool use16 = (ws_size >= need) && ((nent & 3) == 0);
    __half* ent16 = use16 ? (__half*)((char*)d_ws + WFRAG_BYTES) : nullptr;

    const long n4 = nent / 4;
    const int conv_blocks = use16 ? 6400 : 2;
    prep_kernel<<<dim3(conv_blocks), dim3(256), 0, stream>>>(W0, wsp, ent_emb, ent16, n4);

    const int grid = (B + WPB - 1) / WPB;
    if (use16)
        kgs_kernel<true><<<dim3(grid), dim3(64 * WPB), 0, stream>>>(
            u, v, adj, rel_adj, usr_emb, ent_emb, ent16, rel_emb, W0, b0, W1, b1,
            wsp, out, B);
    else
        kgs_kernel<false><<<dim3(grid), dim3(64 * WPB), 0, stream>>>(
            u, v, adj, rel_adj, usr_emb, ent_emb, nullptr, rel_emb, W0, b0, W1, b1,
            wsp, out, B);
}